// Round 12
// baseline (510.222 us; speedup 1.0000x reference)
//
#include <hip/hip_runtime.h>
#include <stdint.h>
#include <stddef.h>

#define NB 32
#define NC 512
#define NN 4096

typedef _Float16 h4_t __attribute__((ext_vector_type(4)));
typedef _Float16 h8_t __attribute__((ext_vector_type(8)));
typedef float    f4_t __attribute__((ext_vector_type(4)));

__device__ __forceinline__ void gload16(const _Float16* g, _Float16* l) {
    __builtin_amdgcn_global_load_lds(
        (const __attribute__((address_space(1))) void*)g,
        (__attribute__((address_space(3))) void*)l, 16, 0, 0);
}

// barrier with compiler memory fences on both sides
#define BARF() { asm volatile("" ::: "memory"); __builtin_amdgcn_s_barrier(); \
                 asm volatile("" ::: "memory"); }

// LDS tile convention (verified R5-R11): [rows][32 k] fp16, 64 B rows.
// Logical k-chunk q (8 elems) of row r lives at phys chunk q ^ ((r>>1)&3).
// Staged via pre-swizzled global source, read back with the same XOR.
// vmcnt rule (R9 lesson): count VMEM *instructions per wave*.

// ---------------------------------------------------------------------------
// Pass 1a (fused): x -> Xh, Xl, Xt. (frozen)
// ---------------------------------------------------------------------------
__global__ __launch_bounds__(256) void cast_transpose(
    const float* __restrict__ x, _Float16* __restrict__ Xh,
    _Float16* __restrict__ Xl, _Float16* __restrict__ Xt)
{
    __shared__ __attribute__((aligned(16))) _Float16 tile[64 * 66];
    const int b = blockIdx.z, c0 = blockIdx.y * 64, n0 = blockIdx.x * 64;
    const int t = threadIdx.x;
    const int lr = t >> 4;
    const int lc = (t & 15) * 4;
    const size_t xbase = (size_t)b * NC * NN;

#pragma unroll
    for (int p = 0; p < 4; ++p) {
        const int r = p * 16 + lr;
        const size_t off = xbase + (size_t)(c0 + r) * NN + (n0 + lc);
        const float4 v = *(const float4*)(x + off);
        const _Float16 h0 = (_Float16)v.x, h1 = (_Float16)v.y;
        const _Float16 h2 = (_Float16)v.z, h3 = (_Float16)v.w;
        h4_t hv = {h0, h1, h2, h3};
        *(h4_t*)(Xh + off) = hv;
        h4_t lv = {(_Float16)(v.x - (float)h0), (_Float16)(v.y - (float)h1),
                   (_Float16)(v.z - (float)h2), (_Float16)(v.w - (float)h3)};
        *(h4_t*)(Xl + off) = lv;
        tile[r * 66 + lc + 0] = h0;
        tile[r * 66 + lc + 1] = h1;
        tile[r * 66 + lc + 2] = h2;
        tile[r * 66 + lc + 3] = h3;
    }
    __syncthreads();
    const size_t tbase = (size_t)b * NN * NC;
#pragma unroll
    for (int p = 0; p < 4; ++p) {
        const int rn = p * 16 + lr;
        h4_t w;
        w[0] = tile[(lc + 0) * 66 + rn];
        w[1] = tile[(lc + 1) * 66 + rn];
        w[2] = tile[(lc + 2) * 66 + rn];
        w[3] = tile[(lc + 3) * 66 + rn];
        *(h4_t*)(Xt + tbase + (size_t)(n0 + rn) * NC + (c0 + lc)) = w;
    }
}

// ---------------------------------------------------------------------------
// Pass 1b (fallback): x -> Xh, Xl only. (frozen)
// ---------------------------------------------------------------------------
__global__ __launch_bounds__(256) void cast_hl(
    const float* __restrict__ x, _Float16* __restrict__ Xh,
    _Float16* __restrict__ Xl)
{
    const size_t total = (size_t)NB * NC * NN / 4;
    for (size_t i = (size_t)blockIdx.x * 256 + threadIdx.x; i < total;
         i += (size_t)gridDim.x * 256) {
        const float4 v = ((const float4*)x)[i];
        const _Float16 h0 = (_Float16)v.x, h1 = (_Float16)v.y;
        const _Float16 h2 = (_Float16)v.z, h3 = (_Float16)v.w;
        h4_t hv = {h0, h1, h2, h3};
        h4_t lv = {(_Float16)(v.x - (float)h0), (_Float16)(v.y - (float)h1),
                   (_Float16)(v.z - (float)h2), (_Float16)(v.w - (float)h3)};
        ((h4_t*)Xh)[i] = hv;
        ((h4_t*)Xl)[i] = lv;
    }
}

// ---------------------------------------------------------------------------
// Pass 2: partial energy, 256x256 symmetric tiles, split-K.
// NEW SHAPE: 4 waves (2x2 grid), wave tile 128x128, acc[8][8] (AGPR-class,
// 1 wave/SIMD so 512-reg budget -- launch_bounds(256,1)). Cuts per-step LDS
// panel reads from 6 to 4 (A read 2x, B read 2x). Counted-vmcnt 2-buffer
// pipeline retained: STG(t+1) -> vmcnt(16|8) -> barrier -> 192 MFMA ->
// barrier. vmcnt(0) only at the tail.
// ---------------------------------------------------------------------------
__global__ __launch_bounds__(256, 1) void gemm1_energy(
    const _Float16* __restrict__ Xh, const _Float16* __restrict__ Xl,
    float* __restrict__ part, int kch, int nsplit)
{
    __shared__ __attribute__((aligned(16))) _Float16 sAh[2][256 * 32];
    __shared__ __attribute__((aligned(16))) _Float16 sAl[2][256 * 32];
    __shared__ __attribute__((aligned(16))) _Float16 sBh[2][256 * 32];
    __shared__ __attribute__((aligned(16))) _Float16 sBl[2][256 * 32];

    const int flat = blockIdx.x;
    const int cpx  = 12 * nsplit;
    const int swz  = (flat & 7) * cpx + (flat >> 3);
    const int per_b = 3 * nsplit;
    const int b   = swz / per_b;
    const int rem = swz % per_b;
    const int s   = rem / 3;
    const int mem = rem % 3;
    const int ti  = (mem >= 1) ? 1 : 0;
    const int tj  = (mem == 2) ? 1 : 0;
    const bool diag = (mem != 1);

    const int t = threadIdx.x;               // 0..255 (4 waves)
    const int wave = t >> 6, lane = t & 63;
    const int wr = wave >> 1, wc = wave & 1;  // 2 x 2 wave grid
    const int fr = lane & 15, fq = lane >> 4;
    const int hi4 = fq * 4;

    const int rr  = t >> 2;                   // staging row 0..63 per sweep
    const int sck = (((t & 3) ^ ((t >> 3) & 3)) * 8);

    const size_t xb = (size_t)b * NC * NN + (size_t)s * kch;
    const _Float16* gAh = Xh + xb + (size_t)(ti * 256 + rr) * NN + sck;
    const _Float16* gAl = Xl + xb + (size_t)(ti * 256 + rr) * NN + sck;
    const _Float16* gBh = Xh + xb + (size_t)(tj * 256 + rr) * NN + sck;
    const _Float16* gBl = Xl + xb + (size_t)(tj * 256 + rr) * NN + sck;
    const size_t P = (size_t)64 * NN;          // 64-row sweep stride

    f4_t acc[8][8];                            // [nf][m]
#pragma unroll
    for (int nf = 0; nf < 8; ++nf)
#pragma unroll
        for (int m = 0; m < 8; ++m) acc[nf][m] = (f4_t){0.f, 0.f, 0.f, 0.f};

#define STGA(buf, k0)                                                        \
    {                                                                        \
        _Pragma("unroll")                                                    \
        for (int p = 0; p < 4; ++p) {                                        \
            gload16(gAh + (k0) + p * P, &sAh[buf][0] + p * 2048 + t * 8);    \
            gload16(gAl + (k0) + p * P, &sAl[buf][0] + p * 2048 + t * 8);    \
        }                                                                    \
    }
#define STGB(buf, k0)                                                        \
    {                                                                        \
        _Pragma("unroll")                                                    \
        for (int p = 0; p < 4; ++p) {                                        \
            gload16(gBh + (k0) + p * P, &sBh[buf][0] + p * 2048 + t * 8);    \
            gload16(gBl + (k0) + p * P, &sBl[buf][0] + p * 2048 + t * 8);    \
        }                                                                    \
    }

// one K-step: 16 B-frag reads (held), then per m: 2 A reads + 24 MFMA
#define COMP(cur, pBh, pBl)                                                  \
    {                                                                        \
        const _Float16* cAh = &sAh[cur][0];                                  \
        const _Float16* cAl = &sAl[cur][0];                                  \
        const _Float16* cBh = (pBh);                                         \
        const _Float16* cBl = (pBl);                                         \
        h8_t bh_[8], bl_[8];                                                 \
        _Pragma("unroll")                                                    \
        for (int nf = 0; nf < 8; ++nf) {                                     \
            const int br = wc * 128 + nf * 16 + fr;                          \
            const int so = (fq ^ ((br >> 1) & 3)) * 8;                       \
            bh_[nf] = *(const h8_t*)(cBh + br * 32 + so);                    \
            bl_[nf] = *(const h8_t*)(cBl + br * 32 + so);                    \
        }                                                                    \
        __builtin_amdgcn_s_setprio(1);                                       \
        _Pragma("unroll")                                                    \
        for (int m = 0; m < 8; ++m) {                                        \
            const int ar = wr * 128 + m * 16 + fr;                           \
            const int so = (fq ^ ((ar >> 1) & 3)) * 8;                       \
            const h8_t ah = *(const h8_t*)(cAh + ar * 32 + so);              \
            const h8_t al = *(const h8_t*)(cAl + ar * 32 + so);              \
            _Pragma("unroll")                                                \
            for (int nf = 0; nf < 8; ++nf) {                                 \
                acc[nf][m] = __builtin_amdgcn_mfma_f32_16x16x32_f16(bh_[nf], ah, acc[nf][m], 0, 0, 0); \
                acc[nf][m] = __builtin_amdgcn_mfma_f32_16x16x32_f16(bl_[nf], ah, acc[nf][m], 0, 0, 0); \
                acc[nf][m] = __builtin_amdgcn_mfma_f32_16x16x32_f16(bh_[nf], al, acc[nf][m], 0, 0, 0); \
            }                                                                \
        }                                                                    \
        __builtin_amdgcn_s_setprio(0);                                       \
    }

    const int nIter = kch >> 5;
    if (diag) {
        STGA(0, 0);
        for (int it = 0; it < nIter; ++it) {
            const int cur = it & 1;
            if (it + 1 < nIter) {
                STGA(cur ^ 1, (it + 1) * 32);
                asm volatile("s_waitcnt vmcnt(8)" ::: "memory");
            } else {
                asm volatile("s_waitcnt vmcnt(0)" ::: "memory");
            }
            BARF();
            COMP(cur, &sAh[cur][0], &sAl[cur][0]);
            BARF();
        }
    } else {
        STGA(0, 0); STGB(0, 0);
        for (int it = 0; it < nIter; ++it) {
            const int cur = it & 1;
            if (it + 1 < nIter) {
                STGA(cur ^ 1, (it + 1) * 32);
                STGB(cur ^ 1, (it + 1) * 32);
                asm volatile("s_waitcnt vmcnt(16)" ::: "memory");
            } else {
                asm volatile("s_waitcnt vmcnt(0)" ::: "memory");
            }
            BARF();
            COMP(cur, &sBh[cur][0], &sBl[cur][0]);
            BARF();
        }
    }
#undef STGA
#undef STGB
#undef COMP

    float* pb = part + ((size_t)s * NB + b) * (NC * NC);
#pragma unroll
    for (int m = 0; m < 8; ++m) {
        const int i = ti * 256 + wr * 128 + m * 16 + fr;
#pragma unroll
        for (int nf = 0; nf < 8; ++nf) {
            const int jjb = tj * 256 + wc * 128 + nf * 16 + hi4;
            *(f4_t*)(pb + (size_t)i * NC + jjb) = acc[nf][m];
            if (!diag) {
#pragma unroll
                for (int j = 0; j < 4; ++j)
                    pb[(size_t)(jjb + j) * NC + i] = acc[nf][m][j];
            }
        }
    }
}

// ---------------------------------------------------------------------------
// Pass 3: attn = softmax(min(e) - e). (frozen)
// ---------------------------------------------------------------------------
__global__ __launch_bounds__(256) void softmax_inv(
    const float* __restrict__ part, _Float16* __restrict__ attn, int nsplit)
{
    const int row = blockIdx.x * 4 + (threadIdx.x >> 6);
    const int lane = threadIdx.x & 63;
    const size_t roff = (size_t)row * NC;

    float4 a0 = {0.f, 0.f, 0.f, 0.f}, a1 = {0.f, 0.f, 0.f, 0.f};
    for (int s = 0; s < nsplit; ++s) {
        const float4* p = (const float4*)(part + (size_t)s * NB * NC * NC + roff);
        const float4 v0 = p[lane], v1 = p[64 + lane];
        a0.x += v0.x; a0.y += v0.y; a0.z += v0.z; a0.w += v0.w;
        a1.x += v1.x; a1.y += v1.y; a1.z += v1.z; a1.w += v1.w;
    }

    float mn = fminf(fminf(fminf(a0.x, a0.y), fminf(a0.z, a0.w)),
                     fminf(fminf(a1.x, a1.y), fminf(a1.z, a1.w)));
#pragma unroll
    for (int off = 32; off; off >>= 1) mn = fminf(mn, __shfl_xor(mn, off));

    const float w0 = __expf(mn - a0.x), w1 = __expf(mn - a0.y);
    const float w2 = __expf(mn - a0.z), w3 = __expf(mn - a0.w);
    const float w4 = __expf(mn - a1.x), w5 = __expf(mn - a1.y);
    const float w6 = __expf(mn - a1.z), w7 = __expf(mn - a1.w);
    float sum = ((w0 + w1) + (w2 + w3)) + ((w4 + w5) + (w6 + w7));
#pragma unroll
    for (int off = 32; off; off >>= 1) sum += __shfl_xor(sum, off);
    const float inv = 1.0f / sum;

    h4_t o0 = {(_Float16)(w0 * inv), (_Float16)(w1 * inv),
               (_Float16)(w2 * inv), (_Float16)(w3 * inv)};
    h4_t o1 = {(_Float16)(w4 * inv), (_Float16)(w5 * inv),
               (_Float16)(w6 * inv), (_Float16)(w7 * inv)};
    ((h4_t*)(attn + roff))[lane] = o0;
    ((h4_t*)(attn + roff))[64 + lane] = o1;
}

// ---------------------------------------------------------------------------
// Pass 4 (fallback only): Xt = Xh^T per batch. (frozen)
// ---------------------------------------------------------------------------
__global__ __launch_bounds__(256) void transpose_h(
    const _Float16* __restrict__ Xh, _Float16* __restrict__ Xt)
{
    __shared__ __attribute__((aligned(16))) _Float16 tile[64 * 66];
    const int b = blockIdx.z, c0 = blockIdx.y * 64, n0 = blockIdx.x * 64;
    const int t = threadIdx.x;
    const int lr = t >> 4;
    const int lc = (t & 15) * 4;
    const size_t hbase = (size_t)b * NC * NN;

#pragma unroll
    for (int p = 0; p < 4; ++p) {
        const int r = p * 16 + lr;
        const h4_t v = *(const h4_t*)(Xh + hbase + (size_t)(c0 + r) * NN + (n0 + lc));
        tile[r * 66 + lc + 0] = v[0];
        tile[r * 66 + lc + 1] = v[1];
        tile[r * 66 + lc + 2] = v[2];
        tile[r * 66 + lc + 3] = v[3];
    }
    __syncthreads();
    const size_t tbase = (size_t)b * NN * NC;
#pragma unroll
    for (int p = 0; p < 4; ++p) {
        const int rn = p * 16 + lr;
        h4_t w;
        w[0] = tile[(lc + 0) * 66 + rn];
        w[1] = tile[(lc + 1) * 66 + rn];
        w[2] = tile[(lc + 2) * 66 + rn];
        w[3] = tile[(lc + 3) * 66 + rn];
        *(h4_t*)(Xt + tbase + (size_t)(n0 + rn) * NC + (c0 + lc)) = w;
    }
}

// ---------------------------------------------------------------------------
// Pass 5: out = gamma * (attn @ x) + x.  FROZEN (R7/R11 version: 256x256,
// 8 waves, 4-buffer / 3-deep prefetch, counted vmcnt(8), 1 barrier/iter).
// ---------------------------------------------------------------------------
__global__ __launch_bounds__(512, 2) void gemm2_out(
    const _Float16* __restrict__ attn, const _Float16* __restrict__ Xt,
    const _Float16* __restrict__ Xh, const float* __restrict__ gammap,
    float* __restrict__ out)
{
    __shared__ __attribute__((aligned(16))) _Float16 sA[4][256 * 32];
    __shared__ __attribute__((aligned(16))) _Float16 sB[4][256 * 32];

    const int flat = blockIdx.x;              // 0..1023
    const int swz  = (flat & 7) * 128 + (flat >> 3);   // XCD-pinned batches
    const int b    = swz >> 5;                // batch
    const int memb = swz & 31;
    const int brow = (memb & 1) * 256;        // c tile (2)
    const int bcol = (memb >> 1) * 256;       // n tile (16)

    const int t = threadIdx.x;
    const int wave = t >> 6, lane = t & 63;
    const int wr = wave >> 2, wc = wave & 3;  // 2 x 4 wave grid
    const int fr = lane & 15, fq = lane >> 4;
    const int hi4 = fq * 4;

    const int rr  = t >> 2;                   // staging row 0..127 / pass
    const int sck = (((t & 3) ^ ((t >> 3) & 3)) * 8);
    const _Float16* gA = attn + (size_t)b * NC * NC + (size_t)(brow + rr) * NC + sck;
    const _Float16* gB = Xt   + (size_t)b * NN * NC + (size_t)(bcol + rr) * NC + sck;
    const size_t P = (size_t)128 * NC;        // 128-row pass stride

    f4_t acc[4][8];
#pragma unroll
    for (int nf = 0; nf < 4; ++nf)
#pragma unroll
        for (int m = 0; m < 8; ++m) acc[nf][m] = (f4_t){0.f, 0.f, 0.f, 0.f};

#define STG2(buf, k0)                                                        \
    {                                                                        \
        gload16(gA + (k0),     &sA[buf][0] + t * 8);                         \
        gload16(gA + (k0) + P, &sA[buf][0] + 4096 + t * 8);                  \
        gload16(gB + (k0),     &sB[buf][0] + t * 8);                         \
        gload16(gB + (k0) + P, &sB[buf][0] + 4096 + t * 8);                  \
    }

    STG2(0, 0);
    STG2(1, 32);
    STG2(2, 64);

#pragma unroll
    for (int it = 0; it < 16; ++it) {
        if (it <= 13)       asm volatile("s_waitcnt vmcnt(8)" ::: "memory");
        else if (it == 14)  asm volatile("s_waitcnt vmcnt(4)" ::: "memory");
        else                asm volatile("s_waitcnt vmcnt(0)" ::: "memory");
        __builtin_amdgcn_s_barrier();
        if (it <= 12) STG2((it + 3) & 3, (it + 3) * 32);

        const _Float16* cA = &sA[it & 3][0];
        const _Float16* cB = &sB[it & 3][0];
        h8_t b_[4];
#pragma unroll
        for (int nf = 0; nf < 4; ++nf) {
            const int br = wc * 64 + nf * 16 + fr;
            b_[nf] = *(const h8_t*)(cB + br * 32 + ((fq ^ ((br >> 1) & 3)) * 8));
        }
#pragma unroll
        for (int m = 0; m < 8; ++m) {
            const int ar = wr * 128 + m * 16 + fr;
            const h8_t a = *(const h8_t*)(cA + ar * 32 + ((fq ^ ((ar >> 1) & 3)) * 8));
#pragma unroll
            for (int nf = 0; nf < 4; ++nf)
                acc[nf][m] = __builtin_amdgcn_mfma_f32_16x16x32_f16(
                    b_[nf], a, acc[nf][m], 0, 0, 0);
        }
    }
#undef STG2

    const float g = gammap[0];
    const _Float16* xb = Xh + (size_t)b * NC * NN;
    float* ob = out + (size_t)b * NC * NN;
#pragma unroll
    for (int m = 0; m < 8; ++m) {
        const int c_ = brow + wr * 128 + m * 16 + fr;
#pragma unroll
        for (int nf = 0; nf < 4; ++nf) {
            const int n_ = bcol + wc * 64 + nf * 16 + hi4;
            const size_t off = (size_t)c_ * NN + n_;
            const h4_t xv = *(const h4_t*)(xb + off);
            f4_t o;
#pragma unroll
            for (int j = 0; j < 4; ++j)
                o[j] = g * acc[nf][m][j] + (float)xv[j];
            *(f4_t*)(ob + off) = o;
        }
    }
}

// ---------------------------------------------------------------------------
extern "C" void kernel_launch(void* const* d_in, const int* in_sizes, int n_in,
                              void* d_out, int out_size, void* d_ws, size_t ws_size,
                              hipStream_t stream)
{
    const float* x     = (const float*)d_in[0];
    const float* gamma = (const float*)d_in[1];
    float* out = (float*)d_out;
    char* ws = (char*)d_ws;

    if (ws_size >= 553648128ull) {
        // Fused path: Xh | Xl | Xt | attn | part[nsplit]
        _Float16* Xh   = (_Float16*)(ws);
        _Float16* Xl   = (_Float16*)(ws + 134217728ull);
        _Float16* Xt   = (_Float16*)(ws + 268435456ull);
        _Float16* attn = (_Float16*)(ws + 402653184ull);
        float*    part = (float*)   (ws + 419430400ull);
        const int nsplit = (ws_size >= 687865856ull) ? 8 : 4;
        const int kch = NN / nsplit;

        cast_transpose<<<dim3(NN / 64, NC / 64, NB), 256, 0, stream>>>(x, Xh, Xl, Xt);
        gemm1_energy<<<dim3(3 * nsplit * NB), 256, 0, stream>>>(Xh, Xl, part, kch, nsplit);
        softmax_inv<<<dim3(NB * NC / 4), 256, 0, stream>>>(part, attn, nsplit);
        gemm2_out<<<dim3(1024), 512, 0, stream>>>(attn, Xt, Xh, gamma, out);
    } else {
        // Fallback: Xh | Xl/Xt (time-shared) | attn | part[4]
        _Float16* Xh   = (_Float16*)(ws);
        _Float16* XlXt = (_Float16*)(ws + 134217728ull);
        _Float16* attn = (_Float16*)(ws + 268435456ull);
        float*    part = (float*)   (ws + 285212672ull);

        cast_hl<<<dim3(2048), 256, 0, stream>>>(x, Xh, XlXt);
        gemm1_energy<<<dim3(3 * 4 * NB), 256, 0, stream>>>(Xh, XlXt, part, NN / 4, 4);
        softmax_inv<<<dim3(NB * NC / 4), 256, 0, stream>>>(part, attn, 4);
        transpose_h<<<dim3(NN / 64, NC / 64, NB), 256, 0, stream>>>(Xh, XlXt);
        gemm2_out<<<dim3(1024), 512, 0, stream>>>(attn, XlXt, Xh, gamma, out);
    }
}

// Round 14
// 507.612 us; speedup vs baseline: 1.0051x; 1.0051x over previous
//
#include <hip/hip_runtime.h>
#include <stdint.h>
#include <stddef.h>

#define NB 32
#define NC 512
#define NN 4096

typedef _Float16 h4_t __attribute__((ext_vector_type(4)));
typedef _Float16 h8_t __attribute__((ext_vector_type(8)));
typedef float    f4_t __attribute__((ext_vector_type(4)));

__device__ __forceinline__ void gload16(const _Float16* g, _Float16* l) {
    __builtin_amdgcn_global_load_lds(
        (const __attribute__((address_space(1))) void*)g,
        (__attribute__((address_space(3))) void*)l, 16, 0, 0);
}

// barrier with compiler memory fences on both sides
#define BARF() { asm volatile("" ::: "memory"); __builtin_amdgcn_s_barrier(); \
                 asm volatile("" ::: "memory"); }

// LDS tile convention (verified R5-R12): [rows][32 k] fp16, 64 B rows.
// Logical k-chunk q (8 elems) of row r lives at phys chunk q ^ ((r>>1)&3).
// Staged via pre-swizzled global source, read back with the same XOR.
// vmcnt rule (R9): count VMEM *instructions per wave*.
// Sync rule (R13 lesson): vmcnt only covers THIS wave's DMA; a barrier AFTER
// the vmcnt guard is required before any wave reads the cooperatively-staged
// tile.

// ---------------------------------------------------------------------------
// Pass 1a (fused): x -> Xh, Xl, Xt. (frozen)
// ---------------------------------------------------------------------------
__global__ __launch_bounds__(256) void cast_transpose(
    const float* __restrict__ x, _Float16* __restrict__ Xh,
    _Float16* __restrict__ Xl, _Float16* __restrict__ Xt)
{
    __shared__ __attribute__((aligned(16))) _Float16 tile[64 * 66];
    const int b = blockIdx.z, c0 = blockIdx.y * 64, n0 = blockIdx.x * 64;
    const int t = threadIdx.x;
    const int lr = t >> 4;
    const int lc = (t & 15) * 4;
    const size_t xbase = (size_t)b * NC * NN;

#pragma unroll
    for (int p = 0; p < 4; ++p) {
        const int r = p * 16 + lr;
        const size_t off = xbase + (size_t)(c0 + r) * NN + (n0 + lc);
        const float4 v = *(const float4*)(x + off);
        const _Float16 h0 = (_Float16)v.x, h1 = (_Float16)v.y;
        const _Float16 h2 = (_Float16)v.z, h3 = (_Float16)v.w;
        h4_t hv = {h0, h1, h2, h3};
        *(h4_t*)(Xh + off) = hv;
        h4_t lv = {(_Float16)(v.x - (float)h0), (_Float16)(v.y - (float)h1),
                   (_Float16)(v.z - (float)h2), (_Float16)(v.w - (float)h3)};
        *(h4_t*)(Xl + off) = lv;
        tile[r * 66 + lc + 0] = h0;
        tile[r * 66 + lc + 1] = h1;
        tile[r * 66 + lc + 2] = h2;
        tile[r * 66 + lc + 3] = h3;
    }
    __syncthreads();
    const size_t tbase = (size_t)b * NN * NC;
#pragma unroll
    for (int p = 0; p < 4; ++p) {
        const int rn = p * 16 + lr;
        h4_t w;
        w[0] = tile[(lc + 0) * 66 + rn];
        w[1] = tile[(lc + 1) * 66 + rn];
        w[2] = tile[(lc + 2) * 66 + rn];
        w[3] = tile[(lc + 3) * 66 + rn];
        *(h4_t*)(Xt + tbase + (size_t)(n0 + rn) * NC + (c0 + lc)) = w;
    }
}

// ---------------------------------------------------------------------------
// Pass 1b (fallback): x -> Xh, Xl only. (frozen)
// ---------------------------------------------------------------------------
__global__ __launch_bounds__(256) void cast_hl(
    const float* __restrict__ x, _Float16* __restrict__ Xh,
    _Float16* __restrict__ Xl)
{
    const size_t total = (size_t)NB * NC * NN / 4;
    for (size_t i = (size_t)blockIdx.x * 256 + threadIdx.x; i < total;
         i += (size_t)gridDim.x * 256) {
        const float4 v = ((const float4*)x)[i];
        const _Float16 h0 = (_Float16)v.x, h1 = (_Float16)v.y;
        const _Float16 h2 = (_Float16)v.z, h3 = (_Float16)v.w;
        h4_t hv = {h0, h1, h2, h3};
        h4_t lv = {(_Float16)(v.x - (float)h0), (_Float16)(v.y - (float)h1),
                   (_Float16)(v.z - (float)h2), (_Float16)(v.w - (float)h3)};
        ((h4_t*)Xh)[i] = hv;
        ((h4_t*)Xl)[i] = lv;
    }
}

// ---------------------------------------------------------------------------
// Pass 2: partial energy, 256x256 symmetric tiles, split-K.
// 8 waves (2x4), wave tile 128x64, acc[4][8]. Per BK=32 step:
//   head: STG(t+1) -> vmcnt(8|4) -> BARF (data-ready, all waves)
//         -> ds_read B frags (held in regs across phases)
//   4 phases: ds_read A(m,m+1) -> lgkmcnt(0)+sched_barrier ->
//             setprio(1) 24 MFMA setprio(0) -> BARF (lockstep)
// Last phase's BARF doubles as the buffer-reuse guard for the next STG.
// ---------------------------------------------------------------------------
__global__ __launch_bounds__(512, 2) void gemm1_energy(
    const _Float16* __restrict__ Xh, const _Float16* __restrict__ Xl,
    float* __restrict__ part, int kch, int nsplit)
{
    __shared__ __attribute__((aligned(16))) _Float16 sAh[2][256 * 32];
    __shared__ __attribute__((aligned(16))) _Float16 sAl[2][256 * 32];
    __shared__ __attribute__((aligned(16))) _Float16 sBh[2][256 * 32];
    __shared__ __attribute__((aligned(16))) _Float16 sBl[2][256 * 32];

    const int flat = blockIdx.x;
    const int cpx  = 12 * nsplit;
    const int swz  = (flat & 7) * cpx + (flat >> 3);
    const int per_b = 3 * nsplit;
    const int b   = swz / per_b;
    const int rem = swz % per_b;
    const int s   = rem / 3;
    const int mem = rem % 3;
    const int ti  = (mem >= 1) ? 1 : 0;
    const int tj  = (mem == 2) ? 1 : 0;
    const bool diag = (mem != 1);

    const int t = threadIdx.x;               // 0..511 (8 waves)
    const int wave = t >> 6, lane = t & 63;
    const int wr = wave >> 2, wc = wave & 3; // 2 x 4 wave grid
    const int fr = lane & 15, fq = lane >> 4;
    const int hi4 = fq * 4;

    const int rr  = t >> 2;                  // staging row 0..127 / pass
    const int sck = (((t & 3) ^ ((t >> 3) & 3)) * 8);

    const size_t xb = (size_t)b * NC * NN + (size_t)s * kch;
    const _Float16* gAh = Xh + xb + (size_t)(ti * 256 + rr) * NN + sck;
    const _Float16* gAl = Xl + xb + (size_t)(ti * 256 + rr) * NN + sck;
    const _Float16* gBh = Xh + xb + (size_t)(tj * 256 + rr) * NN + sck;
    const _Float16* gBl = Xl + xb + (size_t)(tj * 256 + rr) * NN + sck;
    const size_t P = (size_t)128 * NN;

    f4_t acc[4][8];
#pragma unroll
    for (int nf = 0; nf < 4; ++nf)
#pragma unroll
        for (int m = 0; m < 8; ++m) acc[nf][m] = (f4_t){0.f, 0.f, 0.f, 0.f};

#define STGA(buf, k0)                                                        \
    {                                                                        \
        gload16(gAh + (k0),     &sAh[buf][0] + t * 8);                       \
        gload16(gAh + (k0) + P, &sAh[buf][0] + 4096 + t * 8);                \
        gload16(gAl + (k0),     &sAl[buf][0] + t * 8);                       \
        gload16(gAl + (k0) + P, &sAl[buf][0] + 4096 + t * 8);                \
    }
#define STGB(buf, k0)                                                        \
    {                                                                        \
        gload16(gBh + (k0),     &sBh[buf][0] + t * 8);                       \
        gload16(gBh + (k0) + P, &sBh[buf][0] + 4096 + t * 8);                \
        gload16(gBl + (k0),     &sBl[buf][0] + t * 8);                       \
        gload16(gBl + (k0) + P, &sBl[buf][0] + 4096 + t * 8);                \
    }

// one phase: ds_read A frags for rows m0_,m1_ -> lgkm0+schedbar -> 24 MFMA
// -> BARF (phase lockstep; last phase's BARF = buffer-reuse guard)
#define PHASE(m0_, m1_)                                                      \
    {                                                                        \
        h8_t ah0, al0, ah1, al1;                                             \
        { const int ar = wr * 128 + (m0_) * 16 + fr;                         \
          const int so = (fq ^ ((ar >> 1) & 3)) * 8;                         \
          ah0 = *(const h8_t*)(cAh + ar * 32 + so);                          \
          al0 = *(const h8_t*)(cAl + ar * 32 + so); }                        \
        { const int ar = wr * 128 + (m1_) * 16 + fr;                         \
          const int so = (fq ^ ((ar >> 1) & 3)) * 8;                         \
          ah1 = *(const h8_t*)(cAh + ar * 32 + so);                          \
          al1 = *(const h8_t*)(cAl + ar * 32 + so); }                        \
        asm volatile("s_waitcnt lgkmcnt(0)" ::: "memory");                   \
        __builtin_amdgcn_sched_barrier(0);                                   \
        __builtin_amdgcn_s_setprio(1);                                       \
        _Pragma("unroll")                                                    \
        for (int nf = 0; nf < 4; ++nf) {                                     \
            acc[nf][m0_] = __builtin_amdgcn_mfma_f32_16x16x32_f16(bh_[nf], ah0, acc[nf][m0_], 0, 0, 0); \
            acc[nf][m0_] = __builtin_amdgcn_mfma_f32_16x16x32_f16(bl_[nf], ah0, acc[nf][m0_], 0, 0, 0); \
            acc[nf][m0_] = __builtin_amdgcn_mfma_f32_16x16x32_f16(bh_[nf], al0, acc[nf][m0_], 0, 0, 0); \
            acc[nf][m1_] = __builtin_amdgcn_mfma_f32_16x16x32_f16(bh_[nf], ah1, acc[nf][m1_], 0, 0, 0); \
            acc[nf][m1_] = __builtin_amdgcn_mfma_f32_16x16x32_f16(bl_[nf], ah1, acc[nf][m1_], 0, 0, 0); \
            acc[nf][m1_] = __builtin_amdgcn_mfma_f32_16x16x32_f16(bh_[nf], al1, acc[nf][m1_], 0, 0, 0); \
        }                                                                    \
        __builtin_amdgcn_s_setprio(0);                                       \
        BARF();                                                              \
    }

    const int nIter = kch >> 5;
    STGA(0, 0);
    if (!diag) STGB(0, 0);

    for (int it = 0; it < nIter; ++it) {
        const int cur = it & 1;
        // head: issue next-step loads, counted guard, then DATA-READY barrier
        if (it + 1 < nIter) {
            STGA(cur ^ 1, (it + 1) * 32);
            if (!diag) {
                STGB(cur ^ 1, (it + 1) * 32);
                asm volatile("s_waitcnt vmcnt(8)" ::: "memory");
            } else {
                asm volatile("s_waitcnt vmcnt(4)" ::: "memory");
            }
        } else {
            asm volatile("s_waitcnt vmcnt(0)" ::: "memory");
        }
        BARF();   // R13 fix: all waves' DMA for buf[cur] landed past here

        const _Float16* cAh = &sAh[cur][0];
        const _Float16* cAl = &sAl[cur][0];
        const _Float16* cBh = diag ? cAh : &sBh[cur][0];
        const _Float16* cBl = diag ? cAl : &sBl[cur][0];

        // B fragments (held across all 4 phases)
        h8_t bh_[4], bl_[4];
#pragma unroll
        for (int nf = 0; nf < 4; ++nf) {
            const int br = wc * 64 + nf * 16 + fr;
            const int so = (fq ^ ((br >> 1) & 3)) * 8;
            bh_[nf] = *(const h8_t*)(cBh + br * 32 + so);
            bl_[nf] = *(const h8_t*)(cBl + br * 32 + so);
        }
        PHASE(0, 1);
        PHASE(2, 3);
        PHASE(4, 5);
        PHASE(6, 7);
    }
#undef STGA
#undef STGB
#undef PHASE

    float* pb = part + ((size_t)s * NB + b) * (NC * NC);
#pragma unroll
    for (int m = 0; m < 8; ++m) {
        const int i = ti * 256 + wr * 128 + m * 16 + fr;
#pragma unroll
        for (int nf = 0; nf < 4; ++nf) {
            const int jjb = tj * 256 + wc * 64 + nf * 16 + hi4;
            *(f4_t*)(pb + (size_t)i * NC + jjb) = acc[nf][m];
            if (!diag) {
#pragma unroll
                for (int j = 0; j < 4; ++j)
                    pb[(size_t)(jjb + j) * NC + i] = acc[nf][m][j];
            }
        }
    }
}

// ---------------------------------------------------------------------------
// Pass 3: attn = softmax(min(e) - e). (frozen)
// ---------------------------------------------------------------------------
__global__ __launch_bounds__(256) void softmax_inv(
    const float* __restrict__ part, _Float16* __restrict__ attn, int nsplit)
{
    const int row = blockIdx.x * 4 + (threadIdx.x >> 6);
    const int lane = threadIdx.x & 63;
    const size_t roff = (size_t)row * NC;

    float4 a0 = {0.f, 0.f, 0.f, 0.f}, a1 = {0.f, 0.f, 0.f, 0.f};
    for (int s = 0; s < nsplit; ++s) {
        const float4* p = (const float4*)(part + (size_t)s * NB * NC * NC + roff);
        const float4 v0 = p[lane], v1 = p[64 + lane];
        a0.x += v0.x; a0.y += v0.y; a0.z += v0.z; a0.w += v0.w;
        a1.x += v1.x; a1.y += v1.y; a1.z += v1.z; a1.w += v1.w;
    }

    float mn = fminf(fminf(fminf(a0.x, a0.y), fminf(a0.z, a0.w)),
                     fminf(fminf(a1.x, a1.y), fminf(a1.z, a1.w)));
#pragma unroll
    for (int off = 32; off; off >>= 1) mn = fminf(mn, __shfl_xor(mn, off));

    const float w0 = __expf(mn - a0.x), w1 = __expf(mn - a0.y);
    const float w2 = __expf(mn - a0.z), w3 = __expf(mn - a0.w);
    const float w4 = __expf(mn - a1.x), w5 = __expf(mn - a1.y);
    const float w6 = __expf(mn - a1.z), w7 = __expf(mn - a1.w);
    float sum = ((w0 + w1) + (w2 + w3)) + ((w4 + w5) + (w6 + w7));
#pragma unroll
    for (int off = 32; off; off >>= 1) sum += __shfl_xor(sum, off);
    const float inv = 1.0f / sum;

    h4_t o0 = {(_Float16)(w0 * inv), (_Float16)(w1 * inv),
               (_Float16)(w2 * inv), (_Float16)(w3 * inv)};
    h4_t o1 = {(_Float16)(w4 * inv), (_Float16)(w5 * inv),
               (_Float16)(w6 * inv), (_Float16)(w7 * inv)};
    ((h4_t*)(attn + roff))[lane] = o0;
    ((h4_t*)(attn + roff))[64 + lane] = o1;
}

// ---------------------------------------------------------------------------
// Pass 4 (fallback only): Xt = Xh^T per batch. (frozen)
// ---------------------------------------------------------------------------
__global__ __launch_bounds__(256) void transpose_h(
    const _Float16* __restrict__ Xh, _Float16* __restrict__ Xt)
{
    __shared__ __attribute__((aligned(16))) _Float16 tile[64 * 66];
    const int b = blockIdx.z, c0 = blockIdx.y * 64, n0 = blockIdx.x * 64;
    const int t = threadIdx.x;
    const int lr = t >> 4;
    const int lc = (t & 15) * 4;
    const size_t hbase = (size_t)b * NC * NN;

#pragma unroll
    for (int p = 0; p < 4; ++p) {
        const int r = p * 16 + lr;
        const h4_t v = *(const h4_t*)(Xh + hbase + (size_t)(c0 + r) * NN + (n0 + lc));
        tile[r * 66 + lc + 0] = v[0];
        tile[r * 66 + lc + 1] = v[1];
        tile[r * 66 + lc + 2] = v[2];
        tile[r * 66 + lc + 3] = v[3];
    }
    __syncthreads();
    const size_t tbase = (size_t)b * NN * NC;
#pragma unroll
    for (int p = 0; p < 4; ++p) {
        const int rn = p * 16 + lr;
        h4_t w;
        w[0] = tile[(lc + 0) * 66 + rn];
        w[1] = tile[(lc + 1) * 66 + rn];
        w[2] = tile[(lc + 2) * 66 + rn];
        w[3] = tile[(lc + 3) * 66 + rn];
        *(h4_t*)(Xt + tbase + (size_t)(n0 + rn) * NC + (c0 + lc)) = w;
    }
}

// ---------------------------------------------------------------------------
// Pass 5: out = gamma * (attn @ x) + x.  FROZEN (R7/R11 version: 256x256,
// 8 waves, 4-buffer / 3-deep prefetch, counted vmcnt(8), 1 barrier/iter).
// ---------------------------------------------------------------------------
__global__ __launch_bounds__(512, 2) void gemm2_out(
    const _Float16* __restrict__ attn, const _Float16* __restrict__ Xt,
    const _Float16* __restrict__ Xh, const float* __restrict__ gammap,
    float* __restrict__ out)
{
    __shared__ __attribute__((aligned(16))) _Float16 sA[4][256 * 32];
    __shared__ __attribute__((aligned(16))) _Float16 sB[4][256 * 32];

    const int flat = blockIdx.x;              // 0..1023
    const int swz  = (flat & 7) * 128 + (flat >> 3);   // XCD-pinned batches
    const int b    = swz >> 5;                // batch
    const int memb = swz & 31;
    const int brow = (memb & 1) * 256;        // c tile (2)
    const int bcol = (memb >> 1) * 256;       // n tile (16)

    const int t = threadIdx.x;
    const int wave = t >> 6, lane = t & 63;
    const int wr = wave >> 2, wc = wave & 3;  // 2 x 4 wave grid
    const int fr = lane & 15, fq = lane >> 4;
    const int hi4 = fq * 4;

    const int rr  = t >> 2;                   // staging row 0..127 / pass
    const int sck = (((t & 3) ^ ((t >> 3) & 3)) * 8);
    const _Float16* gA = attn + (size_t)b * NC * NC + (size_t)(brow + rr) * NC + sck;
    const _Float16* gB = Xt   + (size_t)b * NN * NC + (size_t)(bcol + rr) * NC + sck;
    const size_t P = (size_t)128 * NC;        // 128-row pass stride

    f4_t acc[4][8];
#pragma unroll
    for (int nf = 0; nf < 4; ++nf)
#pragma unroll
        for (int m = 0; m < 8; ++m) acc[nf][m] = (f4_t){0.f, 0.f, 0.f, 0.f};

#define STG2(buf, k0)                                                        \
    {                                                                        \
        gload16(gA + (k0),     &sA[buf][0] + t * 8);                         \
        gload16(gA + (k0) + P, &sA[buf][0] + 4096 + t * 8);                  \
        gload16(gB + (k0),     &sB[buf][0] + t * 8);                         \
        gload16(gB + (k0) + P, &sB[buf][0] + 4096 + t * 8);                  \
    }

    STG2(0, 0);
    STG2(1, 32);
    STG2(2, 64);

#pragma unroll
    for (int it = 0; it < 16; ++it) {
        if (it <= 13)       asm volatile("s_waitcnt vmcnt(8)" ::: "memory");
        else if (it == 14)  asm volatile("s_waitcnt vmcnt(4)" ::: "memory");
        else                asm volatile("s_waitcnt vmcnt(0)" ::: "memory");
        __builtin_amdgcn_s_barrier();
        if (it <= 12) STG2((it + 3) & 3, (it + 3) * 32);

        const _Float16* cA = &sA[it & 3][0];
        const _Float16* cB = &sB[it & 3][0];
        h8_t b_[4];
#pragma unroll
        for (int nf = 0; nf < 4; ++nf) {
            const int br = wc * 64 + nf * 16 + fr;
            b_[nf] = *(const h8_t*)(cB + br * 32 + ((fq ^ ((br >> 1) & 3)) * 8));
        }
#pragma unroll
        for (int m = 0; m < 8; ++m) {
            const int ar = wr * 128 + m * 16 + fr;
            const h8_t a = *(const h8_t*)(cA + ar * 32 + ((fq ^ ((ar >> 1) & 3)) * 8));
#pragma unroll
            for (int nf = 0; nf < 4; ++nf)
                acc[nf][m] = __builtin_amdgcn_mfma_f32_16x16x32_f16(
                    b_[nf], a, acc[nf][m], 0, 0, 0);
        }
    }
#undef STG2

    const float g = gammap[0];
    const _Float16* xb = Xh + (size_t)b * NC * NN;
    float* ob = out + (size_t)b * NC * NN;
#pragma unroll
    for (int m = 0; m < 8; ++m) {
        const int c_ = brow + wr * 128 + m * 16 + fr;
#pragma unroll
        for (int nf = 0; nf < 4; ++nf) {
            const int n_ = bcol + wc * 64 + nf * 16 + hi4;
            const size_t off = (size_t)c_ * NN + n_;
            const h4_t xv = *(const h4_t*)(xb + off);
            f4_t o;
#pragma unroll
            for (int j = 0; j < 4; ++j)
                o[j] = g * acc[nf][m][j] + (float)xv[j];
            *(f4_t*)(ob + off) = o;
        }
    }
}

// ---------------------------------------------------------------------------
extern "C" void kernel_launch(void* const* d_in, const int* in_sizes, int n_in,
                              void* d_out, int out_size, void* d_ws, size_t ws_size,
                              hipStream_t stream)
{
    const float* x     = (const float*)d_in[0];
    const float* gamma = (const float*)d_in[1];
    float* out = (float*)d_out;
    char* ws = (char*)d_ws;

    if (ws_size >= 553648128ull) {
        // Fused path: Xh | Xl | Xt | attn | part[nsplit]
        _Float16* Xh   = (_Float16*)(ws);
        _Float16* Xl   = (_Float16*)(ws + 134217728ull);
        _Float16* Xt   = (_Float16*)(ws + 268435456ull);
        _Float16* attn = (_Float16*)(ws + 402653184ull);
        float*    part = (float*)   (ws + 419430400ull);
        const int nsplit = (ws_size >= 687865856ull) ? 8 : 4;
        const int kch = NN / nsplit;

        cast_transpose<<<dim3(NN / 64, NC / 64, NB), 256, 0, stream>>>(x, Xh, Xl, Xt);
        gemm1_energy<<<dim3(3 * nsplit * NB), 512, 0, stream>>>(Xh, Xl, part, kch, nsplit);
        softmax_inv<<<dim3(NB * NC / 4), 256, 0, stream>>>(part, attn, nsplit);
        gemm2_out<<<dim3(1024), 512, 0, stream>>>(attn, Xt, Xh, gamma, out);
    } else {
        // Fallback: Xh | Xl/Xt (time-shared) | attn | part[4]
        _Float16* Xh   = (_Float16*)(ws);
        _Float16* XlXt = (_Float16*)(ws + 134217728ull);
        _Float16* attn = (_Float16*)(ws + 268435456ull);
        float*    part = (float*)   (ws + 285212672ull);

        cast_hl<<<dim3(2048), 256, 0, stream>>>(x, Xh, XlXt);
        gemm1_energy<<<dim3(3 * 4 * NB), 512, 0, stream>>>(Xh, XlXt, part, NN / 4, 4);
        softmax_inv<<<dim3(NB * NC / 4), 256, 0, stream>>>(part, attn, 4);
        transpose_h<<<dim3(NN / 64, NC / 64, NB), 256, 0, stream>>>(Xh, XlXt);
        gemm2_out<<<dim3(1024), 512, 0, stream>>>(attn, XlXt, Xh, gamma, out);
    }
}

// Round 15
// 438.617 us; speedup vs baseline: 1.1633x; 1.1573x over previous
//
#include <hip/hip_runtime.h>
#include <stdint.h>
#include <stddef.h>

#define NB 32
#define NC 512
#define NN 4096
#define NSPLIT 4
#define KCH (NN / NSPLIT)   // 1024

typedef _Float16 h4_t __attribute__((ext_vector_type(4)));
typedef _Float16 h8_t __attribute__((ext_vector_type(8)));
typedef float    f4_t __attribute__((ext_vector_type(4)));

__device__ __forceinline__ void gload16(const _Float16* g, _Float16* l) {
    __builtin_amdgcn_global_load_lds(
        (const __attribute__((address_space(1))) void*)g,
        (__attribute__((address_space(3))) void*)l, 16, 0, 0);
}

// LDS tile convention (verified R5-R14): [rows][32 k] fp16, 64 B rows.
// Logical k-chunk q (8 elems) of row r lives at phys chunk q ^ ((r>>1)&3).
// Staged via pre-swizzled global source, read back with the same XOR.

// ---------------------------------------------------------------------------
// Pass 1a (fused): x -> Xh, Xl, Xt. 64x64 LDS transpose. (frozen)
// ---------------------------------------------------------------------------
__global__ __launch_bounds__(256) void cast_transpose(
    const float* __restrict__ x, _Float16* __restrict__ Xh,
    _Float16* __restrict__ Xl, _Float16* __restrict__ Xt)
{
    __shared__ __attribute__((aligned(16))) _Float16 tile[64 * 66];
    const int b = blockIdx.z, c0 = blockIdx.y * 64, n0 = blockIdx.x * 64;
    const int t = threadIdx.x;
    const int lr = t >> 4;
    const int lc = (t & 15) * 4;
    const size_t xbase = (size_t)b * NC * NN;

#pragma unroll
    for (int p = 0; p < 4; ++p) {
        const int r = p * 16 + lr;
        const size_t off = xbase + (size_t)(c0 + r) * NN + (n0 + lc);
        const float4 v = *(const float4*)(x + off);
        const _Float16 h0 = (_Float16)v.x, h1 = (_Float16)v.y;
        const _Float16 h2 = (_Float16)v.z, h3 = (_Float16)v.w;
        h4_t hv = {h0, h1, h2, h3};
        *(h4_t*)(Xh + off) = hv;
        h4_t lv = {(_Float16)(v.x - (float)h0), (_Float16)(v.y - (float)h1),
                   (_Float16)(v.z - (float)h2), (_Float16)(v.w - (float)h3)};
        *(h4_t*)(Xl + off) = lv;
        tile[r * 66 + lc + 0] = h0;
        tile[r * 66 + lc + 1] = h1;
        tile[r * 66 + lc + 2] = h2;
        tile[r * 66 + lc + 3] = h3;
    }
    __syncthreads();
    const size_t tbase = (size_t)b * NN * NC;
#pragma unroll
    for (int p = 0; p < 4; ++p) {
        const int rn = p * 16 + lr;
        h4_t w;
        w[0] = tile[(lc + 0) * 66 + rn];
        w[1] = tile[(lc + 1) * 66 + rn];
        w[2] = tile[(lc + 2) * 66 + rn];
        w[3] = tile[(lc + 3) * 66 + rn];
        *(h4_t*)(Xt + tbase + (size_t)(n0 + rn) * NC + (c0 + lc)) = w;
    }
}

// ---------------------------------------------------------------------------
// Pass 1b (fallback): x -> Xh, Xl only. (frozen)
// ---------------------------------------------------------------------------
__global__ __launch_bounds__(256) void cast_hl(
    const float* __restrict__ x, _Float16* __restrict__ Xh,
    _Float16* __restrict__ Xl)
{
    const size_t total = (size_t)NB * NC * NN / 4;
    for (size_t i = (size_t)blockIdx.x * 256 + threadIdx.x; i < total;
         i += (size_t)gridDim.x * 256) {
        const float4 v = ((const float4*)x)[i];
        const _Float16 h0 = (_Float16)v.x, h1 = (_Float16)v.y;
        const _Float16 h2 = (_Float16)v.z, h3 = (_Float16)v.w;
        h4_t hv = {h0, h1, h2, h3};
        h4_t lv = {(_Float16)(v.x - (float)h0), (_Float16)(v.y - (float)h1),
                   (_Float16)(v.z - (float)h2), (_Float16)(v.w - (float)h3)};
        ((h4_t*)Xh)[i] = hv;
        ((h4_t*)Xl)[i] = lv;
    }
}

// ---------------------------------------------------------------------------
// Pass 2: partial energy. R5-verified version (measured 190 us):
// 128x128 symmetric lower-tri tiles (10 of 16), split-K=4, 4 waves, 32 KB
// LDS (~5 blocks/CU), m97 2-phase loop, corrected swizzle (chunk^=(row>>1)&3).
// ---------------------------------------------------------------------------
__global__ __launch_bounds__(256, 4) void gemm1_energy(
    const _Float16* __restrict__ Xh, const _Float16* __restrict__ Xl,
    float* __restrict__ part)
{
    __shared__ __attribute__((aligned(16))) _Float16 sAh[128 * 32];
    __shared__ __attribute__((aligned(16))) _Float16 sBh[128 * 32];
    __shared__ __attribute__((aligned(16))) _Float16 sAl[128 * 32];
    __shared__ __attribute__((aligned(16))) _Float16 sBl[128 * 32];

    const int flat = blockIdx.x;          // 0..1279
    const int xcd  = flat & 7;
    const int slot = flat >> 3;           // 0..159
    const int grp  = xcd + 8 * (slot / 10);   // 0..127 (bijective)
    const int mem  = slot % 10;           // 0..9 lower-tri tile index
    const int b    = grp >> 2;
    const int s    = grp & (NSPLIT - 1);

    const int ti = (int)((sqrtf(8.0f * (float)mem + 1.0f) - 1.0f) * 0.5f);
    const int tj = mem - ((ti * (ti + 1)) >> 1);
    const bool diag = (ti == tj);

    const int t = threadIdx.x;
    const int wave = t >> 6, lane = t & 63;
    const int srow = t >> 2;
    // pre-swizzled staging source: logical chunk = phys ^ ((row>>1)&3)
    const int scol = (((t & 3) ^ ((t >> 3) & 3)) * 8);

    const size_t xb = (size_t)b * NC * NN + (size_t)s * KCH;
    const _Float16* gAh = Xh + xb + (size_t)(ti * 128 + srow) * NN + scol;
    const _Float16* gBh = Xh + xb + (size_t)(tj * 128 + srow) * NN + scol;
    const _Float16* gAl = Xl + xb + (size_t)(ti * 128 + srow) * NN + scol;
    const _Float16* gBl = Xl + xb + (size_t)(tj * 128 + srow) * NN + scol;

    const int wr = wave >> 1, wc = wave & 1;
    const int fr = lane & 15, fko = (lane >> 4) * 8;
    const int hi4 = (lane >> 4) * 4;
    const int fsw = fko ^ (((fr >> 1) & 3) << 3);   // read swizzle

    const _Float16* rBh = diag ? sAh : sBh;
    const _Float16* rBl = diag ? sAl : sBl;

    f4_t acc[4][4];
#pragma unroll
    for (int m = 0; m < 4; ++m)
#pragma unroll
        for (int n = 0; n < 4; ++n) acc[m][n] = (f4_t){0.f, 0.f, 0.f, 0.f};

    for (int k0 = 0; k0 < KCH; k0 += 32) {
        gload16(gAh + k0,                   sAh + wave * 512);
        gload16(gAh + k0 + 64 * (size_t)NN, sAh + 2048 + wave * 512);
        gload16(gAl + k0,                   sAl + wave * 512);
        gload16(gAl + k0 + 64 * (size_t)NN, sAl + 2048 + wave * 512);
        if (!diag) {
            gload16(gBh + k0,                   sBh + wave * 512);
            gload16(gBh + k0 + 64 * (size_t)NN, sBh + 2048 + wave * 512);
            gload16(gBl + k0,                   sBl + wave * 512);
            gload16(gBl + k0 + 64 * (size_t)NN, sBl + 2048 + wave * 512);
        }
        __syncthreads();

        h8_t ah[4], bh[4], al[4], bl[4];
#pragma unroll
        for (int m = 0; m < 4; ++m) {
            ah[m] = *(const h8_t*)(sAh + (wr * 64 + m * 16 + fr) * 32 + fsw);
            bh[m] = *(const h8_t*)(rBh + (wc * 64 + m * 16 + fr) * 32 + fsw);
            al[m] = *(const h8_t*)(sAl + (wr * 64 + m * 16 + fr) * 32 + fsw);
            bl[m] = *(const h8_t*)(rBl + (wc * 64 + m * 16 + fr) * 32 + fsw);
        }
#pragma unroll
        for (int m = 0; m < 4; ++m)
#pragma unroll
            for (int nf = 0; nf < 4; ++nf) {
                acc[nf][m] = __builtin_amdgcn_mfma_f32_16x16x32_f16(bh[nf], ah[m], acc[nf][m], 0, 0, 0);
                acc[nf][m] = __builtin_amdgcn_mfma_f32_16x16x32_f16(bl[nf], ah[m], acc[nf][m], 0, 0, 0);
                acc[nf][m] = __builtin_amdgcn_mfma_f32_16x16x32_f16(bh[nf], al[m], acc[nf][m], 0, 0, 0);
            }
        __syncthreads();
    }

    float* pb = part + ((size_t)s * NB + b) * (NC * NC);
#pragma unroll
    for (int m = 0; m < 4; ++m) {
        const int i = ti * 128 + wr * 64 + m * 16 + fr;
#pragma unroll
        for (int nf = 0; nf < 4; ++nf) {
            const int jjb = tj * 128 + wc * 64 + nf * 16 + hi4;
            *(f4_t*)(pb + (size_t)i * NC + jjb) = acc[nf][m];
            if (!diag) {
#pragma unroll
                for (int j = 0; j < 4; ++j)
                    pb[(size_t)(jjb + j) * NC + i] = acc[nf][m][j];
            }
        }
    }
}

// ---------------------------------------------------------------------------
// Pass 3: attn = softmax(min(e) - e), e = sum of NSPLIT=4 partials.
// ---------------------------------------------------------------------------
__global__ __launch_bounds__(256) void softmax_inv(
    const float* __restrict__ part, _Float16* __restrict__ attn)
{
    const int row = blockIdx.x * 4 + (threadIdx.x >> 6);
    const int lane = threadIdx.x & 63;
    const size_t roff = (size_t)row * NC;

    float4 a0 = {0.f, 0.f, 0.f, 0.f}, a1 = {0.f, 0.f, 0.f, 0.f};
#pragma unroll
    for (int s = 0; s < NSPLIT; ++s) {
        const float4* p = (const float4*)(part + (size_t)s * NB * NC * NC + roff);
        const float4 v0 = p[lane], v1 = p[64 + lane];
        a0.x += v0.x; a0.y += v0.y; a0.z += v0.z; a0.w += v0.w;
        a1.x += v1.x; a1.y += v1.y; a1.z += v1.z; a1.w += v1.w;
    }

    float mn = fminf(fminf(fminf(a0.x, a0.y), fminf(a0.z, a0.w)),
                     fminf(fminf(a1.x, a1.y), fminf(a1.z, a1.w)));
#pragma unroll
    for (int off = 32; off; off >>= 1) mn = fminf(mn, __shfl_xor(mn, off));

    const float w0 = __expf(mn - a0.x), w1 = __expf(mn - a0.y);
    const float w2 = __expf(mn - a0.z), w3 = __expf(mn - a0.w);
    const float w4 = __expf(mn - a1.x), w5 = __expf(mn - a1.y);
    const float w6 = __expf(mn - a1.z), w7 = __expf(mn - a1.w);
    float sum = ((w0 + w1) + (w2 + w3)) + ((w4 + w5) + (w6 + w7));
#pragma unroll
    for (int off = 32; off; off >>= 1) sum += __shfl_xor(sum, off);
    const float inv = 1.0f / sum;

    h4_t o0 = {(_Float16)(w0 * inv), (_Float16)(w1 * inv),
               (_Float16)(w2 * inv), (_Float16)(w3 * inv)};
    h4_t o1 = {(_Float16)(w4 * inv), (_Float16)(w5 * inv),
               (_Float16)(w6 * inv), (_Float16)(w7 * inv)};
    ((h4_t*)(attn + roff))[lane] = o0;
    ((h4_t*)(attn + roff))[64 + lane] = o1;
}

// ---------------------------------------------------------------------------
// Pass 4 (fallback only): Xt = Xh^T per batch. (frozen)
// ---------------------------------------------------------------------------
__global__ __launch_bounds__(256) void transpose_h(
    const _Float16* __restrict__ Xh, _Float16* __restrict__ Xt)
{
    __shared__ __attribute__((aligned(16))) _Float16 tile[64 * 66];
    const int b = blockIdx.z, c0 = blockIdx.y * 64, n0 = blockIdx.x * 64;
    const int t = threadIdx.x;
    const int lr = t >> 4;
    const int lc = (t & 15) * 4;
    const size_t hbase = (size_t)b * NC * NN;

#pragma unroll
    for (int p = 0; p < 4; ++p) {
        const int r = p * 16 + lr;
        const h4_t v = *(const h4_t*)(Xh + hbase + (size_t)(c0 + r) * NN + (n0 + lc));
        tile[r * 66 + lc + 0] = v[0];
        tile[r * 66 + lc + 1] = v[1];
        tile[r * 66 + lc + 2] = v[2];
        tile[r * 66 + lc + 3] = v[3];
    }
    __syncthreads();
    const size_t tbase = (size_t)b * NN * NC;
#pragma unroll
    for (int p = 0; p < 4; ++p) {
        const int rn = p * 16 + lr;
        h4_t w;
        w[0] = tile[(lc + 0) * 66 + rn];
        w[1] = tile[(lc + 1) * 66 + rn];
        w[2] = tile[(lc + 2) * 66 + rn];
        w[3] = tile[(lc + 3) * 66 + rn];
        *(h4_t*)(Xt + tbase + (size_t)(n0 + rn) * NC + (c0 + lc)) = w;
    }
}

// ---------------------------------------------------------------------------
// Pass 5: out = gamma * (attn @ x) + x.  R7-verified version (~170 us):
// 256x256, 8 waves, 4-buffer / 3-deep prefetch, counted vmcnt(8),
// 1 barrier/iter, 128 KB LDS, acc[4][8].
// ---------------------------------------------------------------------------
__global__ __launch_bounds__(512, 2) void gemm2_out(
    const _Float16* __restrict__ attn, const _Float16* __restrict__ Xt,
    const _Float16* __restrict__ Xh, const float* __restrict__ gammap,
    float* __restrict__ out)
{
    __shared__ __attribute__((aligned(16))) _Float16 sA[4][256 * 32];
    __shared__ __attribute__((aligned(16))) _Float16 sB[4][256 * 32];

    const int flat = blockIdx.x;              // 0..1023
    const int swz  = (flat & 7) * 128 + (flat >> 3);   // XCD-pinned batches
    const int b    = swz >> 5;                // batch
    const int memb = swz & 31;
    const int brow = (memb & 1) * 256;        // c tile (2)
    const int bcol = (memb >> 1) * 256;       // n tile (16)

    const int t = threadIdx.x;
    const int wave = t >> 6, lane = t & 63;
    const int wr = wave >> 2, wc = wave & 3;  // 2 x 4 wave grid
    const int fr = lane & 15, fq = lane >> 4;
    const int hi4 = fq * 4;

    const int rr  = t >> 2;                   // staging row 0..127 / pass
    const int sck = (((t & 3) ^ ((t >> 3) & 3)) * 8);
    const _Float16* gA = attn + (size_t)b * NC * NC + (size_t)(brow + rr) * NC + sck;
    const _Float16* gB = Xt   + (size_t)b * NN * NC + (size_t)(bcol + rr) * NC + sck;
    const size_t P = (size_t)128 * NC;        // 128-row pass stride

    f4_t acc[4][8];
#pragma unroll
    for (int nf = 0; nf < 4; ++nf)
#pragma unroll
        for (int m = 0; m < 8; ++m) acc[nf][m] = (f4_t){0.f, 0.f, 0.f, 0.f};

#define STG2(buf, k0)                                                        \
    {                                                                        \
        gload16(gA + (k0),     &sA[buf][0] + t * 8);                         \
        gload16(gA + (k0) + P, &sA[buf][0] + 4096 + t * 8);                  \
        gload16(gB + (k0),     &sB[buf][0] + t * 8);                         \
        gload16(gB + (k0) + P, &sB[buf][0] + 4096 + t * 8);                  \
    }

    STG2(0, 0);
    STG2(1, 32);
    STG2(2, 64);

#pragma unroll
    for (int it = 0; it < 16; ++it) {
        if (it <= 13)       asm volatile("s_waitcnt vmcnt(8)" ::: "memory");
        else if (it == 14)  asm volatile("s_waitcnt vmcnt(4)" ::: "memory");
        else                asm volatile("s_waitcnt vmcnt(0)" ::: "memory");
        __builtin_amdgcn_s_barrier();
        if (it <= 12) STG2((it + 3) & 3, (it + 3) * 32);

        const _Float16* cA = &sA[it & 3][0];
        const _Float16* cB = &sB[it & 3][0];
        h8_t b_[4];
#pragma unroll
        for (int nf = 0; nf < 4; ++nf) {
            const int br = wc * 64 + nf * 16 + fr;
            b_[nf] = *(const h8_t*)(cB + br * 32 + ((fq ^ ((br >> 1) & 3)) * 8));
        }
#pragma unroll
        for (int m = 0; m < 8; ++m) {
            const int ar = wr * 128 + m * 16 + fr;
            const h8_t a = *(const h8_t*)(cA + ar * 32 + ((fq ^ ((ar >> 1) & 3)) * 8));
#pragma unroll
            for (int nf = 0; nf < 4; ++nf)
                acc[nf][m] = __builtin_amdgcn_mfma_f32_16x16x32_f16(
                    b_[nf], a, acc[nf][m], 0, 0, 0);
        }
    }
#undef STG2

    const float g = gammap[0];
    const _Float16* xb = Xh + (size_t)b * NC * NN;
    float* ob = out + (size_t)b * NC * NN;
#pragma unroll
    for (int m = 0; m < 8; ++m) {
        const int c_ = brow + wr * 128 + m * 16 + fr;
#pragma unroll
        for (int nf = 0; nf < 4; ++nf) {
            const int n_ = bcol + wc * 64 + nf * 16 + hi4;
            const size_t off = (size_t)c_ * NN + n_;
            const h4_t xv = *(const h4_t*)(xb + off);
            f4_t o;
#pragma unroll
            for (int j = 0; j < 4; ++j)
                o[j] = g * acc[nf][m][j] + (float)xv[j];
            *(f4_t*)(ob + off) = o;
        }
    }
}

// ---------------------------------------------------------------------------
extern "C" void kernel_launch(void* const* d_in, const int* in_sizes, int n_in,
                              void* d_out, int out_size, void* d_ws, size_t ws_size,
                              hipStream_t stream)
{
    const float* x     = (const float*)d_in[0];
    const float* gamma = (const float*)d_in[1];
    float* out = (float*)d_out;
    char* ws = (char*)d_ws;

    if (ws_size >= 553648128ull) {
        // Fused path: Xh | Xl | Xt | attn | part[4]
        _Float16* Xh   = (_Float16*)(ws);
        _Float16* Xl   = (_Float16*)(ws + 134217728ull);
        _Float16* Xt   = (_Float16*)(ws + 268435456ull);
        _Float16* attn = (_Float16*)(ws + 402653184ull);
        float*    part = (float*)   (ws + 419430400ull);

        cast_transpose<<<dim3(NN / 64, NC / 64, NB), 256, 0, stream>>>(x, Xh, Xl, Xt);
        gemm1_energy<<<dim3(10 * NSPLIT * NB), 256, 0, stream>>>(Xh, Xl, part);
        softmax_inv<<<dim3(NB * NC / 4), 256, 0, stream>>>(part, attn);
        gemm2_out<<<dim3(1024), 512, 0, stream>>>(attn, Xt, Xh, gamma, out);
    } else {
        // Fallback: Xh | Xl/Xt (time-shared) | attn | part[4]
        _Float16* Xh   = (_Float16*)(ws);
        _Float16* XlXt = (_Float16*)(ws + 134217728ull);
        _Float16* attn = (_Float16*)(ws + 268435456ull);
        float*    part = (float*)   (ws + 285212672ull);

        cast_hl<<<dim3(2048), 256, 0, stream>>>(x, Xh, XlXt);
        gemm1_energy<<<dim3(10 * NSPLIT * NB), 256, 0, stream>>>(Xh, XlXt, part);
        softmax_inv<<<dim3(NB * NC / 4), 256, 0, stream>>>(part, attn);
        transpose_h<<<dim3(NN / 64, NC / 64, NB), 256, 0, stream>>>(Xh, XlXt);
        gemm2_out<<<dim3(1024), 512, 0, stream>>>(attn, XlXt, Xh, gamma, out);
    }
}